// Round 6
// baseline (190.421 us; speedup 1.0000x reference)
//
#include <hip/hip_runtime.h>
#include <hip/hip_bf16.h>
#include <math.h>

#define BB 4
#define NN 512
#define NP 516   // padded eb_lds row (bank-conflict fix)
#define DD 64
#define HH 8
#define DKK 8

typedef float f32x4 __attribute__((ext_vector_type(4)));
typedef short s16x8 __attribute__((ext_vector_type(8)));

// exact split fp32 -> bf16 hi (truncate) + bf16 lo (residual) — for weights/Eb
__device__ __forceinline__ void split8(const float* fv, s16x8& hi, s16x8& lo) {
#pragma unroll
    for (int j = 0; j < 8; ++j) {
        const unsigned u = __float_as_uint(fv[j]);
        hi[j] = (short)(u >> 16);
        const float r = fv[j] - __uint_as_float(u & 0xFFFF0000u);
        lo[j] = (short)(__float_as_uint(r) >> 16);
    }
}

// ---------------- Kernel 1: QKV projection ----------------
__global__ __launch_bounds__(64) void qkv_kernel(
    const float* __restrict__ n,
    const float* __restrict__ Wq,
    const float* __restrict__ Wk,
    const float* __restrict__ Wv,
    float* __restrict__ Q,
    float* __restrict__ K,
    float* __restrict__ V)
{
    const int row = blockIdx.x;        // b*N + i
    const int j = threadIdx.x;         // 0..63
    __shared__ __align__(16) float nr[DD];
    nr[j] = n[(size_t)row * DD + j];
    __syncthreads();
    float q = 0.f, k = 0.f, v = 0.f;
#pragma unroll
    for (int d = 0; d < DD; ++d) {
        const float nv = nr[d];
        q = fmaf(nv, Wq[d * DD + j], q);
        k = fmaf(nv, Wk[d * DD + j], k);
        v = fmaf(nv, Wv[d * DD + j], v);
    }
    Q[(size_t)row * DD + j] = q;
    K[(size_t)row * DD + j] = k;
    V[(size_t)row * DD + j] = v;
}

// ---------------- Kernel 2: MFMA edge + attention ----------------
// Block = one (b,i), 256 threads = 4 waves. Wave w owns m in [128w, 128w+128)
// as 8 tiles of 16 rows, with register double-buffer prefetch of the next
// e-tile. GEMM1 (K=64): e_bf16rne @ [We|Wg]_(hi+lo) -> 4 MFMA.
// GEMM2 (K=8 pad 32): Eb_(hi,lo) @ Oe_(hi+lo) -> 12 MFMA.
__global__ __launch_bounds__(256, 4) void attn_kernel(
    const float* __restrict__ e,
    const float* __restrict__ Q,
    const float* __restrict__ K,
    const float* __restrict__ V,
    const float* __restrict__ We,   // [64][8]
    const float* __restrict__ Wg,   // [64][8]
    const float* __restrict__ Oe,   // [8][64]
    const float* __restrict__ On,   // [64][64]
    float* __restrict__ n_out,      // [B][N][64]
    float* __restrict__ e_out)      // [B][N][N][64]
{
    const int row = blockIdx.x;        // b*N + i
    const int b = row >> 9;
    const int t = threadIdx.x;
    const int lane = t & 63;
    const int wv = t >> 6;             // wave 0..3
    const int cc = lane & 15;          // M-row (A) / N-col (B,C) within tile
    const int kg = lane >> 4;          // k-group 0..3

    __shared__ __align__(16) float q_lds[DD];
    __shared__ __align__(16) float eb_lds[HH][NP];          // padded: A_clip then Eb
    __shared__ __align__(16) unsigned short ehi_w[4][16][8]; // per-wave Eb hi
    __shared__ __align__(16) unsigned short elo_w[4][16][8]; // per-wave Eb lo
    __shared__ float gpart[4][HH];
    __shared__ float gsum[HH];
    __shared__ float vh_lds[DD];

    if (t < DD) q_lds[t] = Q[(size_t)row * DD + t];
    __syncthreads();

    // ---- Phase A: A_clip = clip(Q.K * scale) into eb_lds ----
    const float scale = 0.35355339059327373f;
    const float* __restrict__ Kb = K + (size_t)b * NN * DD;
    for (int mm = 0; mm < 2; ++mm) {
        const int m = t + mm * 256;
        const float4* __restrict__ kr = (const float4*)(Kb + (size_t)m * DD);
#pragma unroll
        for (int h = 0; h < HH; ++h) {
            const float4 k0 = kr[2 * h];
            const float4 k1 = kr[2 * h + 1];
            const float4 q0 = *(const float4*)&q_lds[h * 8];
            const float4 q1 = *(const float4*)&q_lds[h * 8 + 4];
            float a = q0.x * k0.x;
            a = fmaf(q0.y, k0.y, a);
            a = fmaf(q0.z, k0.z, a);
            a = fmaf(q0.w, k0.w, a);
            a = fmaf(q1.x, k1.x, a);
            a = fmaf(q1.y, k1.y, a);
            a = fmaf(q1.z, k1.z, a);
            a = fmaf(q1.w, k1.w, a);
            a *= scale;
            eb_lds[h][m] = fminf(fmaxf(a, -5.f), 5.f);
        }
    }
    __syncthreads();

    // ---- Weight fragments (once per block, register-resident) ----
    // B1: Wc[k][c] with Wc = [We | Wg]; k = ks*32 + kg*8 + j, c = cc
    s16x8 b1h[2], b1l[2];
#pragma unroll
    for (int ks = 0; ks < 2; ++ks) {
        float fv[8];
#pragma unroll
        for (int j = 0; j < 8; ++j) {
            const int k = ks * 32 + kg * 8 + j;
            fv[j] = (cc < 8) ? We[k * HH + cc] : Wg[k * HH + (cc - 8)];
        }
        split8(fv, b1h[ks], b1l[ks]);
    }
    // B2: Oe[k][d], d = nt*16 + cc; k = kg*8 + j, valid only kg==0 (K padded 8->32)
    s16x8 b2h[4], b2l[4];
#pragma unroll
    for (int nt = 0; nt < 4; ++nt) {
        float fv[8];
#pragma unroll
        for (int j = 0; j < 8; ++j)
            fv[j] = (kg == 0) ? Oe[j * DD + nt * 16 + cc] : 0.f;
        split8(fv, b2h[nt], b2l[nt]);
    }

    // ---- Main loop over this wave's 8 m-tiles, prefetch depth 1 ----
    float gs_loc = 0.f;   // lanes with cc>=8 accumulate sigmoid(G) for h=cc-8
    const float* __restrict__ e_row = e + (size_t)row * NN * DD;
    float* __restrict__ eo = e_out + (size_t)row * NN * DD;

    const int T0 = wv * 8;
    float4 pf0, pf1, pf2, pf3;
    {
        const float* s = e_row + (size_t)(T0 * 16 + cc) * DD + kg * 8;
        pf0 = *(const float4*)s;
        pf1 = *(const float4*)(s + 4);
        pf2 = *(const float4*)(s + 32);
        pf3 = *(const float4*)(s + 36);
    }

#pragma unroll 1
    for (int T = T0; T < T0 + 8; ++T) {
        const int m0 = T * 16;
        const float4 c0 = pf0, c1 = pf1, c2v = pf2, c3 = pf3;
        // issue next tile's loads (in flight during this tile's compute)
        {
            const int Tn = (T < T0 + 7) ? T + 1 : T;
            const float* s = e_row + (size_t)(Tn * 16 + cc) * DD + kg * 8;
            pf0 = *(const float4*)s;
            pf1 = *(const float4*)(s + 4);
            pf2 = *(const float4*)(s + 32);
            pf3 = *(const float4*)(s + 36);
        }

        // A1 frags: bf16-RNE of e (no lo-term; error ~2^-9 rel, OK vs threshold)
        s16x8 a1h[2];
        {
            float fv[16] = {c0.x, c0.y, c0.z, c0.w, c1.x, c1.y, c1.z, c1.w,
                            c2v.x, c2v.y, c2v.z, c2v.w, c3.x, c3.y, c3.z, c3.w};
#pragma unroll
            for (int j = 0; j < 8; ++j) {
                a1h[0][j] = (short)((__float_as_uint(fv[j]) + 0x8000u) >> 16);
                a1h[1][j] = (short)((__float_as_uint(fv[8 + j]) + 0x8000u) >> 16);
            }
        }

        // GEMM1: C[m][c] = e @ [We|Wg]  (4 MFMA)
        f32x4 acc = {0.f, 0.f, 0.f, 0.f};
#pragma unroll
        for (int ks = 0; ks < 2; ++ks) {
            acc = __builtin_amdgcn_mfma_f32_16x16x32_bf16(a1h[ks], b1h[ks], acc, 0, 0, 0);
            acc = __builtin_amdgcn_mfma_f32_16x16x32_bf16(a1h[ks], b1l[ks], acc, 0, 0, 0);
        }

        // post: C row = kg*4 + r, col = cc
        if (cc < 8) {
#pragma unroll
            for (int r = 0; r < 4; ++r) {
                const int mr = kg * 4 + r;
                const int m = m0 + mr;
                const float ebv = eb_lds[cc][m] + acc[r];   // Eb = A_clip + E
                eb_lds[cc][m] = ebv;                         // for softmax
                const unsigned u = __float_as_uint(ebv);
                ehi_w[wv][mr][cc] = (unsigned short)(u >> 16);
                const float rr = ebv - __uint_as_float(u & 0xFFFF0000u);
                elo_w[wv][mr][cc] = (unsigned short)(__float_as_uint(rr) >> 16);
            }
        } else {
#pragma unroll
            for (int r = 0; r < 4; ++r)
                gs_loc += 1.f / (1.f + __expf(-acc[r]));
        }

        // A2 frags: Eb[m0+l][h=j] for lanes l<16 (k-groups >=1 are zero padding)
        s16x8 a2h = {0, 0, 0, 0, 0, 0, 0, 0};
        s16x8 a2l = {0, 0, 0, 0, 0, 0, 0, 0};
        if (lane < 16) {
            a2h = *(const s16x8*)&ehi_w[wv][lane][0];
            a2l = *(const s16x8*)&elo_w[wv][lane][0];
        }
        // GEMM2: e_out[m][d] = Eb @ Oe  (12 MFMA)
#pragma unroll
        for (int nt = 0; nt < 4; ++nt) {
            f32x4 c2 = {0.f, 0.f, 0.f, 0.f};
            c2 = __builtin_amdgcn_mfma_f32_16x16x32_bf16(a2h, b2h[nt], c2, 0, 0, 0);
            c2 = __builtin_amdgcn_mfma_f32_16x16x32_bf16(a2l, b2h[nt], c2, 0, 0, 0);
            c2 = __builtin_amdgcn_mfma_f32_16x16x32_bf16(a2h, b2l[nt], c2, 0, 0, 0);
#pragma unroll
            for (int r = 0; r < 4; ++r) {
                const int m = m0 + kg * 4 + r;
                eo[(size_t)m * DD + nt * 16 + cc] = c2[r];
            }
        }
    }

    // ---- G reduction: lanes {8+h, 24+h, 40+h, 56+h} hold partials ----
    {
        float x = gs_loc;
        x += __shfl_xor(x, 16, 64);
        x += __shfl_xor(x, 32, 64);
        if (lane >= 8 && lane < 16) gpart[wv][lane - 8] = x;
    }
    __syncthreads();
    if (t < HH) gsum[t] = gpart[0][t] + gpart[1][t] + gpart[2][t] + gpart[3][t];
    __syncthreads();

    // ---- softmax + PV: wave wv handles h = wv and wv+4 ----
    const float* __restrict__ Vb = V + (size_t)b * NN * DD;
#pragma unroll
    for (int hh = 0; hh < 2; ++hh) {
        const int h = wv + hh * 4;
        float x[8];
#pragma unroll
        for (int k = 0; k < 8; ++k) x[k] = eb_lds[h][lane + (k << 6)];
        float mx = x[0];
#pragma unroll
        for (int k = 1; k < 8; ++k) mx = fmaxf(mx, x[k]);
        mx = fmaxf(mx, __shfl_xor(mx, 1, 64));
        mx = fmaxf(mx, __shfl_xor(mx, 2, 64));
        mx = fmaxf(mx, __shfl_xor(mx, 4, 64));
        mx = fmaxf(mx, __shfl_xor(mx, 8, 64));
        mx = fmaxf(mx, __shfl_xor(mx, 16, 64));
        mx = fmaxf(mx, __shfl_xor(mx, 32, 64));
        float p[8];
        float s = 0.f;
#pragma unroll
        for (int k = 0; k < 8; ++k) { p[k] = __expf(x[k] - mx); s += p[k]; }
        s += __shfl_xor(s, 1, 64);
        s += __shfl_xor(s, 2, 64);
        s += __shfl_xor(s, 4, 64);
        s += __shfl_xor(s, 8, 64);
        s += __shfl_xor(s, 16, 64);
        s += __shfl_xor(s, 32, 64);

        float pv[8];
#pragma unroll
        for (int dk = 0; dk < 8; ++dk) pv[dk] = 0.f;
#pragma unroll
        for (int k = 0; k < 8; ++k) {
            const float* vr = Vb + (size_t)(lane + (k << 6)) * DD + h * DKK;
            const float4 va = *(const float4*)vr;
            const float4 vb2 = *(const float4*)(vr + 4);
            const float pk = p[k];
            pv[0] = fmaf(pk, va.x, pv[0]);
            pv[1] = fmaf(pk, va.y, pv[1]);
            pv[2] = fmaf(pk, va.z, pv[2]);
            pv[3] = fmaf(pk, va.w, pv[3]);
            pv[4] = fmaf(pk, vb2.x, pv[4]);
            pv[5] = fmaf(pk, vb2.y, pv[5]);
            pv[6] = fmaf(pk, vb2.z, pv[6]);
            pv[7] = fmaf(pk, vb2.w, pv[7]);
        }
#pragma unroll
        for (int dk = 0; dk < 8; ++dk) {
            float x2 = pv[dk];
            x2 += __shfl_xor(x2, 1, 64);
            x2 += __shfl_xor(x2, 2, 64);
            x2 += __shfl_xor(x2, 4, 64);
            x2 += __shfl_xor(x2, 8, 64);
            x2 += __shfl_xor(x2, 16, 64);
            x2 += __shfl_xor(x2, 32, 64);
            pv[dk] = x2;
        }
        if (lane == 0) {
            const float sc = log1pf(gsum[h]) / s;
#pragma unroll
            for (int dk = 0; dk < 8; ++dk) vh_lds[h * DKK + dk] = pv[dk] * sc;
        }
    }
    __syncthreads();

    // ---- n_out[b,i,:] = vh @ On ----
    if (t < DD) {
        const int j = t;
        float acc = 0.f;
#pragma unroll
        for (int d = 0; d < DD; ++d) acc = fmaf(vh_lds[d], On[d * DD + j], acc);
        n_out[(size_t)row * DD + j] = acc;
    }
}

extern "C" void kernel_launch(void* const* d_in, const int* in_sizes, int n_in,
                              void* d_out, int out_size, void* d_ws, size_t ws_size,
                              hipStream_t stream) {
    const float* n  = (const float*)d_in[0];
    const float* e  = (const float*)d_in[1];
    const float* Wq = (const float*)d_in[2];
    const float* Wk = (const float*)d_in[3];
    const float* Wv = (const float*)d_in[4];
    const float* On = (const float*)d_in[5];
    const float* We = (const float*)d_in[6];
    const float* Wg = (const float*)d_in[7];
    const float* Oe = (const float*)d_in[8];

    float* out = (float*)d_out;
    float* n_out = out;                                  // B*N*D floats
    float* e_out = out + (size_t)BB * NN * DD;           // B*N*N*D floats

    float* Q = (float*)d_ws;
    float* K = Q + (size_t)BB * NN * DD;
    float* V = K + (size_t)BB * NN * DD;

    qkv_kernel<<<BB * NN, 64, 0, stream>>>(n, Wq, Wk, Wv, Q, K, V);
    attn_kernel<<<BB * NN, 256, 0, stream>>>(e, Q, K, V, We, Wg, Oe, On, n_out, e_out);
}